// Round 1
// baseline (145.485 us; speedup 1.0000x reference)
//
#include <hip/hip_runtime.h>

#define NPTS 200000
#define NBOX 256
#define NFEAT 64
#define KCAP 262144

// d_out layout (floats)
#define OUT_COORDS 0
#define OUT_FEAT   (KCAP * 4)                 // 1,048,576
#define OUT_INSIDE (KCAP * 4 + KCAP * NFEAT)  // 17,825,792

// d_ws layout (ints)
#define WS_TOTAL  0
#define WS_COUNT  64
#define WS_OFFSET 320
#define WS_SEL    576

// ---------------------------------------------------------------------------
// Kernel 1: is_inside matrix (float 0/1) + per-box counts.
// Grid: x = point chunks of 1024 (256 thr * 4 pts), y = 8 box-groups of 32.
// ---------------------------------------------------------------------------
__global__ __launch_bounds__(256) void k1_inside(
    const int4* __restrict__ c4, const float* __restrict__ bbox,
    const int* __restrict__ assoc, float* __restrict__ inside_out,
    int* __restrict__ count) {
  __shared__ float bx0[32], by0[32], bz0[32], bx1[32], by1[32], bz1[32];
  __shared__ int bs[32];
  const int g = blockIdx.y;
  const int t = threadIdx.x;
  if (t < 32) {
    int b = g * 32 + t;
    bx0[t] = bbox[b * 6 + 0];
    by0[t] = bbox[b * 6 + 1];
    bz0[t] = bbox[b * 6 + 2];
    bx1[t] = bbox[b * 6 + 3];
    by1[t] = bbox[b * 6 + 4];
    bz1[t] = bbox[b * 6 + 5];
    bs[t] = assoc[b];
  }
  __syncthreads();
  const int p0 = blockIdx.x * 1024 + t * 4;
  if (p0 >= NPTS) return;  // NPTS % 4 == 0 -> quads are all-or-nothing
  float fx[4], fy[4], fz[4];
  int ss[4];
#pragma unroll
  for (int i = 0; i < 4; ++i) {
    int4 c = c4[p0 + i];
    fx[i] = (float)c.x;
    fy[i] = (float)c.y;
    fz[i] = (float)c.z;
    ss[i] = c.w;
  }
#pragma unroll 4
  for (int j = 0; j < 32; ++j) {
    const int b = g * 32 + j;
    const float x0 = bx0[j], y0 = by0[j], z0 = bz0[j];
    const float x1 = bx1[j], y1 = by1[j], z1 = bz1[j];
    const int sb = bs[j];
    float r[4];
    int cnt = 0;
#pragma unroll
    for (int i = 0; i < 4; ++i) {
      bool in = (ss[i] == sb) && (fx[i] >= x0) && (fx[i] < x1) &&
                (fy[i] >= y0) && (fy[i] < y1) && (fz[i] >= z0) && (fz[i] < z1);
      r[i] = in ? 1.0f : 0.0f;
      cnt += in ? 1 : 0;
    }
    *reinterpret_cast<float4*>(inside_out + (size_t)b * NPTS + p0) =
        make_float4(r[0], r[1], r[2], r[3]);
    if (cnt) atomicAdd(&count[b], cnt);
  }
}

// ---------------------------------------------------------------------------
// Kernel 2: exclusive scan of 256 counts -> offsets + total. 1 block.
// ---------------------------------------------------------------------------
__global__ __launch_bounds__(256) void k2_scan(const int* __restrict__ count,
                                               int* __restrict__ offset,
                                               int* __restrict__ total) {
  __shared__ int sh[256];
  const int t = threadIdx.x;
  const int v0 = count[t];
  sh[t] = v0;
  __syncthreads();
  for (int off = 1; off < 256; off <<= 1) {
    int v = 0;
    if (t >= off) v = sh[t - off];
    __syncthreads();
    sh[t] += v;
    __syncthreads();
  }
  offset[t] = sh[t] - v0;
  if (t == 255) total[0] = sh[255];
}

// ---------------------------------------------------------------------------
// Kernel 3: per-box ordered compaction into packed (b<<18)|n list.
// Grid: 256 blocks (one per box) x 256 threads.
// ---------------------------------------------------------------------------
__global__ __launch_bounds__(256) void k3_compact(
    const int* __restrict__ coords, const float* __restrict__ bbox,
    const int* __restrict__ assoc, const int* __restrict__ offset,
    int* __restrict__ sel) {
  const int b = blockIdx.x;
  const int t = threadIdx.x;
  const int s = assoc[b];
  const float x0 = bbox[b * 6 + 0], y0 = bbox[b * 6 + 1], z0 = bbox[b * 6 + 2];
  const float x1 = bbox[b * 6 + 3], y1 = bbox[b * 6 + 4], z1 = bbox[b * 6 + 5];
  // binary search sample range [beg, end) -- coords sorted by sample column
  int lo = 0, hi = NPTS;
  while (lo < hi) {
    int m = (lo + hi) >> 1;
    if (coords[m * 4 + 3] < s) lo = m + 1; else hi = m;
  }
  const int beg = lo;
  lo = 0; hi = NPTS;
  while (lo < hi) {
    int m = (lo + hi) >> 1;
    if (coords[m * 4 + 3] < s + 1) lo = m + 1; else hi = m;
  }
  const int end = lo;
  const int base = offset[b];
  __shared__ int wtot[4];
  int run = 0;
  const int lane = t & 63, wid = t >> 6;
  const unsigned long long lmask = (1ull << lane) - 1ull;
  for (int ch = beg; ch < end; ch += 256) {
    const int n = ch + t;
    bool in = false;
    if (n < end) {
      int4 c = reinterpret_cast<const int4*>(coords)[n];
      float fx = (float)c.x, fy = (float)c.y, fz = (float)c.z;
      in = (fx >= x0) && (fx < x1) && (fy >= y0) && (fy < y1) && (fz >= z0) &&
           (fz < z1);
    }
    const unsigned long long m = __ballot(in);
    if (lane == 0) wtot[wid] = __popcll(m);
    __syncthreads();
    int wbase = 0;
#pragma unroll
    for (int w = 0; w < 4; ++w)
      if (w < wid) wbase += wtot[w];
    const int ctot = wtot[0] + wtot[1] + wtot[2] + wtot[3];
    if (in) {
      const int pos = base + run + wbase + __popcll(m & lmask);
      if (pos < KCAP) sel[pos] = (b << 18) | n;
    }
    run += ctot;
    __syncthreads();
  }
}

// ---------------------------------------------------------------------------
// Kernel 4: gather features + coords rows; zero-fill past total.
// Grid: KCAP/4 blocks x 256 threads; each 64-lane wave owns one output row.
// ---------------------------------------------------------------------------
__global__ __launch_bounds__(256) void k4_gather(
    const int* __restrict__ coords, const float* __restrict__ feat,
    const int* __restrict__ sel, const int* __restrict__ total,
    float* __restrict__ out_coords, float* __restrict__ out_feat) {
  const int t = threadIdx.x;
  const int lane = t & 63, wid = t >> 6;
  const int k = blockIdx.x * 4 + wid;
  const int totc = min(total[0], KCAP);
  if (k < totc) {
    const int packed = sel[k];
    const int n = packed & 0x3FFFF;
    const int b = packed >> 18;
    out_feat[(size_t)k * NFEAT + lane] = feat[(size_t)n * NFEAT + lane];
    if (lane == 0) {
      int4 c = reinterpret_cast<const int4*>(coords)[n];
      reinterpret_cast<float4*>(out_coords)[k] =
          make_float4((float)c.x, (float)c.y, (float)c.z, (float)b);
    }
  } else {
    out_feat[(size_t)k * NFEAT + lane] = 0.0f;
    if (lane == 0)
      reinterpret_cast<float4*>(out_coords)[k] = make_float4(0, 0, 0, 0);
  }
}

extern "C" void kernel_launch(void* const* d_in, const int* in_sizes, int n_in,
                              void* d_out, int out_size, void* d_ws,
                              size_t ws_size, hipStream_t stream) {
  const int* coords = (const int*)d_in[0];
  const float* feat = (const float*)d_in[1];
  const float* bbox = (const float*)d_in[2];
  const int* assoc = (const int*)d_in[3];
  float* out = (float*)d_out;
  int* ws = (int*)d_ws;

  // zero total/count/offset each call (deterministic)
  hipMemsetAsync(d_ws, 0, WS_SEL * sizeof(int), stream);

  dim3 g1((NPTS + 1023) / 1024, 8);
  k1_inside<<<g1, 256, 0, stream>>>(reinterpret_cast<const int4*>(coords),
                                    bbox, assoc, out + OUT_INSIDE,
                                    ws + WS_COUNT);
  k2_scan<<<1, 256, 0, stream>>>(ws + WS_COUNT, ws + WS_OFFSET, ws + WS_TOTAL);
  k3_compact<<<NBOX, 256, 0, stream>>>(coords, bbox, assoc, ws + WS_OFFSET,
                                       ws + WS_SEL);
  k4_gather<<<KCAP / 4, 256, 0, stream>>>(coords, feat, ws + WS_SEL,
                                          ws + WS_TOTAL, out + OUT_COORDS,
                                          out + OUT_FEAT);
}